// Round 1
// baseline (317.904 us; speedup 1.0000x reference)
//
#include <hip/hip_runtime.h>
#include <hip/hip_bf16.h>
#include <math.h>

// Problem dims
#define BATCH 8192
#define INF   1024
#define LEAFW 256
#define OUTF  1024
#define NLEAF 16
#define NNODE 15
#define NTOT  4096      // NLEAF * LEAFW
#define KEXT  4160      // 4096 + 64 (mixture @ B2 folded into GEMM2's K)

typedef __bf16 bf16;
typedef __bf16 bf16x4 __attribute__((ext_vector_type(4)));
typedef __bf16 bf16x8 __attribute__((ext_vector_type(8)));
typedef float  f32x4  __attribute__((ext_vector_type(4)));

// ---------------------------------------------------------------------------
// Fused weight prep (unchanged): transpose w1/w2 to bf16, append b2 columns.
__global__ __launch_bounds__(256) void prep_weights_kernel(
    const float* __restrict__ w1, const float* __restrict__ w2,
    const float* __restrict__ b2s, bf16* __restrict__ W1T,
    bf16* __restrict__ W2T) {
  __shared__ float tile[32][33];
  int b  = blockIdx.x;
  int t  = threadIdx.x;
  int tx = t & 31, ty = t >> 5;  // (32, 8)

  if (b < 4096) {  // w1 transpose
    int l = b >> 8, rem = b & 255;
    int hb = (rem & 7) * 32, fb = (rem >> 3) * 32;
    const float* in1 = w1 + (size_t)l * INF * LEAFW;
#pragma unroll
    for (int i = 0; i < 4; ++i)
      tile[ty + 8 * i][tx] = in1[(size_t)(fb + ty + 8 * i) * LEAFW + hb + tx];
    __syncthreads();
#pragma unroll
    for (int i = 0; i < 4; ++i)
      W1T[(size_t)(l * LEAFW + hb + ty + 8 * i) * INF + fb + tx] =
          (bf16)tile[tx][ty + 8 * i];
  } else if (b < 8192) {  // w2 transpose
    int bb = b - 4096;
    int l = bb >> 8, rem = bb & 255;
    int ob = (rem & 31) * 32, hb = (rem >> 5) * 32;
    const float* in2 = w2 + (size_t)l * LEAFW * OUTF;
#pragma unroll
    for (int i = 0; i < 4; ++i)
      tile[ty + 8 * i][tx] = in2[(size_t)(hb + ty + 8 * i) * OUTF + ob + tx];
    __syncthreads();
#pragma unroll
    for (int i = 0; i < 4; ++i)
      W2T[(size_t)(ob + ty + 8 * i) * KEXT + l * LEAFW + hb + tx] =
          (bf16)tile[tx][ty + 8 * i];
  } else {  // W2T extension columns
    int i = (b - 8192) * 256 + t;  // < 1024*64
    int o = i >> 6, j = i & 63;
    W2T[(size_t)o * KEXT + NTOT + j] =
        (j < NLEAF) ? (bf16)b2s[(size_t)j * OUTF + o] : (bf16)0.f;
  }
}

// ---------------------------------------------------------------------------
// Fused gating + x->bf16 convert (unchanged).
__global__ __launch_bounds__(256) void gating_kernel(
    const float4* __restrict__ x4, const float4* __restrict__ nw4,
    const float* __restrict__ nb, float* __restrict__ mg,
    bf16* __restrict__ Aact, bf16x4* __restrict__ Xbf4) {
  int row  = blockIdx.x * 4 + (threadIdx.x >> 6);
  int lane = threadIdx.x & 63;
  const float4* xr4 = x4 + (size_t)row * (INF / 4);

  float p[NNODE];
#pragma unroll
  for (int j = 0; j < NNODE; ++j) p[j] = 0.f;
#pragma unroll
  for (int c = 0; c < INF / 256; ++c) {  // 4 iters, float4 per lane
    int idx = c * 64 + lane;
    float4 xv = xr4[idx];
#pragma unroll
    for (int j = 0; j < NNODE; ++j) {
      float4 wv = nw4[j * (INF / 4) + idx];
      p[j] += xv.x * wv.x + xv.y * wv.y + xv.z * wv.z + xv.w * wv.w;
    }
    bf16x4 o = {(bf16)xv.x, (bf16)xv.y, (bf16)xv.z, (bf16)xv.w};
    Xbf4[(size_t)row * (INF / 4) + idx] = o;
  }
#pragma unroll
  for (int j = 0; j < NNODE; ++j) {
    float v = p[j];
#pragma unroll
    for (int off = 32; off > 0; off >>= 1) v += __shfl_xor(v, off);
    p[j] = 1.f / (1.f + expf(-(v + nb[j])));  // sigmoid
  }
  float mixv[NLEAF];
#pragma unroll
  for (int L = 0; L < NLEAF; ++L) {
    int n1 = 1 + (L >> 3), n2 = 3 + (L >> 2), n3 = 7 + (L >> 1);
    float m = ((L >> 3) & 1) ? p[0] : (1.f - p[0]);
    m *= ((L >> 2) & 1) ? p[n1] : (1.f - p[n1]);
    m *= ((L >> 1) & 1) ? p[n2] : (1.f - p[n2]);
    m *= (L & 1) ? p[n3] : (1.f - p[n3]);
    mixv[L] = m;
  }
  bf16* arow = Aact + (size_t)row * KEXT + NTOT;
  if (lane == 0) {
#pragma unroll
    for (int L = 0; L < NLEAF; ++L) {
      mg[row * NLEAF + L] = mixv[L];
      arow[L] = (bf16)mixv[L];
    }
  }
  if (lane >= 16) arow[lane] = (bf16)0.f;  // cols 4112..4159
}

// ---------------------------------------------------------------------------
// 8-phase counted-vmcnt bf16 MFMA GEMM (T2+T3+T4+T5; m201-style template).
// C[M][N] = A[M][K] (row-major, lda) @ BT[N][K]^T (row-major, ldb).
// TBM x 256 tile, BK=64, 8 waves (2M x 4N), 512 threads.
// Half-tile granularity staging: A-half = TBM/2 rows, B-half = 128 BT-rows.
// Phase p consumes quadrant; order (0,0),(1,0),(1,1),(0,1) so
//   A0 free after ph3, A1 after ph2, B0 after ph1, B1 after ph3.
// Stage schedule (tile t): p0 -> (t+1).A0 [other buf], p1 -> (t+1).B1,
//   p2 -> (t+2).B0 [cur buf, freed ph1], p3 -> (t+2).A1 [freed ph2].
// Counted vmcnt: end of p1 -> 2LA+2LB (guarantees (t).B1 for p2),
//   end of p3 -> LA+2LB (guarantees (t+1).A0 for next p0). Never 0.

template <int N>
__device__ __forceinline__ void wait_vmcnt() {
  if constexpr (N >= 0) {
    asm volatile("s_waitcnt vmcnt(%0)" ::"n"(N) : "memory");
  }
}

#define GEMM_PHASE(PM, PN, STAGE_STMT, VM)                                     \
  do {                                                                         \
    bf16x8 af[FM / 2][2], bq[2][2];                                            \
    _Pragma("unroll") for (int ii = 0; ii < FM / 2; ++ii) {                    \
      _Pragma("unroll") for (int kk = 0; kk < 2; ++kk) {                       \
        af[ii][kk] = rdA(cur, (PM) * (FM / 2) + ii, kk);                       \
      }                                                                        \
    }                                                                          \
    _Pragma("unroll") for (int jj = 0; jj < 2; ++jj) {                         \
      _Pragma("unroll") for (int kk = 0; kk < 2; ++kk) {                       \
        bq[jj][kk] = rdB(cur, (PN) * 2 + jj, kk);                              \
      }                                                                        \
    }                                                                          \
    STAGE_STMT;                                                                \
    asm volatile("" ::: "memory");                                             \
    __builtin_amdgcn_s_barrier();                                              \
    asm volatile("s_waitcnt lgkmcnt(0)" ::: "memory");                         \
    __builtin_amdgcn_s_setprio(1);                                             \
    _Pragma("unroll") for (int kk = 0; kk < 2; ++kk) {                         \
      _Pragma("unroll") for (int ii = 0; ii < FM / 2; ++ii) {                  \
        _Pragma("unroll") for (int jj = 0; jj < 2; ++jj) {                     \
          acc[(PM) * (FM / 2) + ii][(PN) * 2 + jj] =                           \
              __builtin_amdgcn_mfma_f32_16x16x32_bf16(                         \
                  af[ii][kk], bq[jj][kk],                                      \
                  acc[(PM) * (FM / 2) + ii][(PN) * 2 + jj], 0, 0, 0);          \
        }                                                                      \
      }                                                                        \
    }                                                                          \
    __builtin_amdgcn_s_setprio(0);                                             \
    wait_vmcnt<(VM)>();                                                        \
    asm volatile("" ::: "memory");                                             \
    __builtin_amdgcn_s_barrier();                                              \
    asm volatile("" ::: "memory");                                             \
  } while (0)

template <int TBM, int EPI>
__global__ __launch_bounds__(512, 2) void gemm8_kernel(
    const bf16* __restrict__ A, int lda, const bf16* __restrict__ BT, int ldb,
    int K, const float* __restrict__ bias, const float* __restrict__ mg,
    bf16* __restrict__ outB, int ldob, float* __restrict__ outF, int ldof,
    int ntn) {
  static_assert(TBM == 256 || TBM == 128, "TBM");
  constexpr int HHA = TBM / 2;    // rows per A half-tile
  constexpr int LA  = TBM / 128;  // global_load_lds issues per A half
  constexpr int LB  = 2;          // issues per B half (BN = 256 fixed)
  constexpr int FM  = TBM / 32;   // per-wave M fragments (8 or 4)
  constexpr int FN  = 4;          // per-wave N fragments
  constexpr int ASZ = TBM * 64;   // elems per A k-tile buffer
  constexpr int BSZ = 256 * 64;   // elems per B k-tile buffer
  constexpr int VM1 = 2 * LA + 2 * LB;  // end of phase 1
  constexpr int VM2 = LA + 2 * LB;      // end of phase 3

  __shared__ __align__(16) bf16 As[2 * ASZ];  // 64 KiB (TBM=256) / 32 KiB
  __shared__ __align__(16) bf16 Bs[2 * BSZ];  // 64 KiB

  const int t    = threadIdx.x;
  const int lane = t & 63;
  const int w    = t >> 6;
  const int wm   = w >> 2;  // 0..1
  const int wn   = w & 3;   // 0..3

  // XCD-bijective swizzle (grid % 8 == 0 for both launches)
  const int nwg  = gridDim.x;
  const int orig = blockIdx.x;
  const int swz  = (orig & 7) * (nwg >> 3) + (orig >> 3);
  const int bm   = (swz / ntn) * TBM;
  const int bn   = (swz % ntn) * 256;

  // staging decomposition: thread -> (row-in-issue, chunk), XOR pre-swizzled
  // global column so linear LDS + XOR read = conflict-free (involution).
  const int lr   = t >> 3;  // 0..63
  const int cs   = t & 7;
  const int scol = ((cs ^ (lr & 7)) << 3);  // element offset within 64-col

  auto stageA = [&](int kt, int h, int buf) {
#pragma unroll
    for (int q = 0; q < LA; ++q) {
      const bf16* src =
          A + (size_t)(bm + h * HHA + q * 64 + lr) * lda + kt * 64 + scol;
      __builtin_amdgcn_global_load_lds(
          (const __attribute__((address_space(1))) void*)src,
          (__attribute__((address_space(3))) void*)((char*)As +
                                                    buf * (ASZ * 2) +
                                                    h * (HHA * 128) +
                                                    q * 8192 + t * 16),
          16, 0, 0);
    }
  };
  auto stageB = [&](int kt, int h, int buf) {
#pragma unroll
    for (int q = 0; q < LB; ++q) {
      const bf16* src =
          BT + (size_t)(bn + h * 128 + q * 64 + lr) * ldb + kt * 64 + scol;
      __builtin_amdgcn_global_load_lds(
          (const __attribute__((address_space(1))) void*)src,
          (__attribute__((address_space(3))) void*)((char*)Bs +
                                                    buf * (BSZ * 2) +
                                                    h * 16384 + q * 8192 +
                                                    t * 16),
          16, 0, 0);
    }
  };
  // frag i at tile row (i>>2)*128 + wm*64 + (i&3)*16 (TBM=256) so quadrant
  // pm touches only A-half pm; analogous for TBM=128 and for B (pn).
  auto rdA = [&](int buf, int i, int kk) -> bf16x8 {
    int h, r;
    if constexpr (TBM == 256) {
      h = i >> 2;
      r = wm * 64 + (i & 3) * 16 + (lane & 15);
    } else {
      h = i >> 1;
      r = wm * 32 + (i & 1) * 16 + (lane & 15);
    }
    int ch = ((kk << 2) + (lane >> 4)) ^ (lane & 7);
    return *reinterpret_cast<const bf16x8*>(
        &As[buf * ASZ + h * (HHA * 64) + r * 64 + ch * 8]);
  };
  auto rdB = [&](int buf, int j, int kk) -> bf16x8 {
    int h = j >> 1;
    int r = wn * 32 + (j & 1) * 16 + (lane & 15);
    int ch = ((kk << 2) + (lane >> 4)) ^ (lane & 7);
    return *reinterpret_cast<const bf16x8*>(
        &Bs[buf * BSZ + h * 8192 + r * 64 + ch * 8]);
  };

  f32x4 acc[FM][FN];
#pragma unroll
  for (int i = 0; i < FM; ++i)
#pragma unroll
    for (int j = 0; j < FN; ++j) acc[i][j] = (f32x4){0.f, 0.f, 0.f, 0.f};

  const int NT = K >> 6;

  // Prologue: t0.{B0,A1,A0,B1} -> buf0, t1.{B0,A1} -> buf1 (steady order).
  stageB(0, 0, 0);
  stageA(0, 1, 0);
  stageA(0, 0, 0);
  stageB(0, 1, 0);
  const int k1p = NT > 1 ? 1 : 0;
  stageB(k1p, 0, 1);
  stageA(k1p, 1, 1);
  wait_vmcnt<VM2>();  // t0.A0/A1/B0 landed; last 3 halves may be in flight
  asm volatile("" ::: "memory");
  __builtin_amdgcn_s_barrier();
  asm volatile("" ::: "memory");

  for (int kt = 0; kt < NT; ++kt) {
    const int cur = kt & 1, nxt = cur ^ 1;
    const int k1 = kt + 1 < NT ? kt + 1 : NT - 1;  // clamp keeps vmcnt
    const int k2 = kt + 2 < NT ? kt + 2 : NT - 1;  // counts uniform
    GEMM_PHASE(0, 0, stageA(k1, 0, nxt), -1);
    GEMM_PHASE(1, 0, stageB(k1, 1, nxt), VM1);
    GEMM_PHASE(1, 1, stageB(k2, 0, cur), -1);
    GEMM_PHASE(0, 1, stageA(k2, 1, cur), VM2);
  }

  // Epilogue. C/D layout (m89): col = lane&15, row = (lane>>4)*4 + reg
#pragma unroll
  for (int i = 0; i < FM; ++i) {
    int rb;
    if constexpr (TBM == 256)
      rb = (i >> 2) * 128 + wm * 64 + (i & 3) * 16;
    else
      rb = (i >> 1) * 64 + wm * 32 + (i & 1) * 16;
    rb += bm + ((lane >> 4) << 2);
#pragma unroll
    for (int rr = 0; rr < 4; ++rr) {
      const int grow = rb + rr;
      if constexpr (EPI == 0) {
        const float g = mg[grow * NLEAF + (bn >> 8)];  // one leaf per block
#pragma unroll
        for (int j = 0; j < FN; ++j) {
          const int gcol =
              bn + (j >> 1) * 128 + wn * 32 + (j & 1) * 16 + (lane & 15);
          float v = acc[i][j][rr] + bias[gcol];
          v = v > 0.f ? v : 0.f;
          outB[(size_t)grow * ldob + gcol] = (bf16)(v * g);
        }
      } else {
#pragma unroll
        for (int j = 0; j < FN; ++j) {
          const int gcol =
              bn + (j >> 1) * 128 + wn * 32 + (j & 1) * 16 + (lane & 15);
          outF[(size_t)grow * ldof + gcol] = acc[i][j][rr];
        }
      }
    }
  }
}

// ---------------------------------------------------------------------------
extern "C" void kernel_launch(void* const* d_in, const int* in_sizes, int n_in,
                              void* d_out, int out_size, void* d_ws,
                              size_t ws_size, hipStream_t stream) {
  const float* x   = (const float*)d_in[0];  // [8192][1024]
  const float* nw  = (const float*)d_in[1];  // [15][1024]
  const float* nb  = (const float*)d_in[2];  // [15]
  const float* w1s = (const float*)d_in[3];  // [16][1024][256]
  const float* b1s = (const float*)d_in[4];  // [16][256] -> flat [4096]
  const float* w2s = (const float*)d_in[5];  // [16][256][1024]
  const float* b2s = (const float*)d_in[6];  // [16][1024]
  float* out = (float*)d_out;                // [8192][1024]

  char* ws = (char*)d_ws;
  bf16*  Xbf  = (bf16*)(ws);                  // 16,777,216 B
  bf16*  W1T  = (bf16*)(ws + 16777216);       //  8,388,608 B  [4096][1024]
  bf16*  W2T  = (bf16*)(ws + 25165824);       //  8,519,680 B  [1024][4160]
  float* mg   = (float*)(ws + 33685504);      //    524,288 B  [8192][16]
  bf16*  Aact = (bf16*)(ws + 34209792);       // 68,157,440 B  [8192][4160]

  prep_weights_kernel<<<dim3(8448), 256, 0, stream>>>(w1s, w2s, b2s, W1T, W2T);
  gating_kernel<<<dim3(BATCH / 4), 256, 0, stream>>>(
      (const float4*)x, (const float4*)nw, nb, mg, Aact, (bf16x4*)Xbf);

  // GEMM1: Aact[:, :4096] = relu(Xbf @ W1T^T + b1) * mixture
  // 256x256 tile: grid 32*16 = 512 blocks (512 % 8 == 0)
  gemm8_kernel<256, 0><<<dim3((BATCH / 256) * (NTOT / 256)), 512, 0, stream>>>(
      Xbf, INF, W1T, INF, INF, b1s, mg, Aact, KEXT, nullptr, 0, NTOT / 256);
  // GEMM2: out = Aact @ W2T^T (K = 4160 includes mixture @ B2 term)
  // 128x256 tile: grid 64*4 = 256 blocks = full 256-CU machine
  gemm8_kernel<128, 1><<<dim3((BATCH / 128) * (OUTF / 256)), 512, 0, stream>>>(
      Aact, KEXT, W2T, KEXT, KEXT, nullptr, nullptr, nullptr, 0, out, OUTF,
      OUTF / 256);
}

// Round 2
// 267.348 us; speedup vs baseline: 1.1891x; 1.1891x over previous
//
#include <hip/hip_runtime.h>
#include <hip/hip_bf16.h>
#include <math.h>

// Problem dims
#define BATCH 8192
#define INF   1024
#define LEAFW 256
#define OUTF  1024
#define NLEAF 16
#define NNODE 15
#define NTOT  4096      // NLEAF * LEAFW
#define KEXT  4160      // 4096 + 64 (mixture @ B2 folded into GEMM2's K)

typedef __bf16 bf16;
typedef __bf16 bf16x4 __attribute__((ext_vector_type(4)));
typedef __bf16 bf16x8 __attribute__((ext_vector_type(8)));
typedef float  f32x4  __attribute__((ext_vector_type(4)));

// ---------------------------------------------------------------------------
// Fused weight prep (unchanged): transpose w1/w2 to bf16, append b2 columns.
__global__ __launch_bounds__(256) void prep_weights_kernel(
    const float* __restrict__ w1, const float* __restrict__ w2,
    const float* __restrict__ b2s, bf16* __restrict__ W1T,
    bf16* __restrict__ W2T) {
  __shared__ float tile[32][33];
  int b  = blockIdx.x;
  int t  = threadIdx.x;
  int tx = t & 31, ty = t >> 5;  // (32, 8)

  if (b < 4096) {  // w1 transpose
    int l = b >> 8, rem = b & 255;
    int hb = (rem & 7) * 32, fb = (rem >> 3) * 32;
    const float* in1 = w1 + (size_t)l * INF * LEAFW;
#pragma unroll
    for (int i = 0; i < 4; ++i)
      tile[ty + 8 * i][tx] = in1[(size_t)(fb + ty + 8 * i) * LEAFW + hb + tx];
    __syncthreads();
#pragma unroll
    for (int i = 0; i < 4; ++i)
      W1T[(size_t)(l * LEAFW + hb + ty + 8 * i) * INF + fb + tx] =
          (bf16)tile[tx][ty + 8 * i];
  } else if (b < 8192) {  // w2 transpose
    int bb = b - 4096;
    int l = bb >> 8, rem = bb & 255;
    int ob = (rem & 31) * 32, hb = (rem >> 5) * 32;
    const float* in2 = w2 + (size_t)l * LEAFW * OUTF;
#pragma unroll
    for (int i = 0; i < 4; ++i)
      tile[ty + 8 * i][tx] = in2[(size_t)(hb + ty + 8 * i) * OUTF + ob + tx];
    __syncthreads();
#pragma unroll
    for (int i = 0; i < 4; ++i)
      W2T[(size_t)(ob + ty + 8 * i) * KEXT + l * LEAFW + hb + tx] =
          (bf16)tile[tx][ty + 8 * i];
  } else {  // W2T extension columns
    int i = (b - 8192) * 256 + t;  // < 1024*64
    int o = i >> 6, j = i & 63;
    W2T[(size_t)o * KEXT + NTOT + j] =
        (j < NLEAF) ? (bf16)b2s[(size_t)j * OUTF + o] : (bf16)0.f;
  }
}

// ---------------------------------------------------------------------------
// Fused gating + x->bf16 convert (unchanged).
__global__ __launch_bounds__(256) void gating_kernel(
    const float4* __restrict__ x4, const float4* __restrict__ nw4,
    const float* __restrict__ nb, float* __restrict__ mg,
    bf16* __restrict__ Aact, bf16x4* __restrict__ Xbf4) {
  int row  = blockIdx.x * 4 + (threadIdx.x >> 6);
  int lane = threadIdx.x & 63;
  const float4* xr4 = x4 + (size_t)row * (INF / 4);

  float p[NNODE];
#pragma unroll
  for (int j = 0; j < NNODE; ++j) p[j] = 0.f;
#pragma unroll
  for (int c = 0; c < INF / 256; ++c) {  // 4 iters, float4 per lane
    int idx = c * 64 + lane;
    float4 xv = xr4[idx];
#pragma unroll
    for (int j = 0; j < NNODE; ++j) {
      float4 wv = nw4[j * (INF / 4) + idx];
      p[j] += xv.x * wv.x + xv.y * wv.y + xv.z * wv.z + xv.w * wv.w;
    }
    bf16x4 o = {(bf16)xv.x, (bf16)xv.y, (bf16)xv.z, (bf16)xv.w};
    Xbf4[(size_t)row * (INF / 4) + idx] = o;
  }
#pragma unroll
  for (int j = 0; j < NNODE; ++j) {
    float v = p[j];
#pragma unroll
    for (int off = 32; off > 0; off >>= 1) v += __shfl_xor(v, off);
    p[j] = 1.f / (1.f + expf(-(v + nb[j])));  // sigmoid
  }
  float mixv[NLEAF];
#pragma unroll
  for (int L = 0; L < NLEAF; ++L) {
    int n1 = 1 + (L >> 3), n2 = 3 + (L >> 2), n3 = 7 + (L >> 1);
    float m = ((L >> 3) & 1) ? p[0] : (1.f - p[0]);
    m *= ((L >> 2) & 1) ? p[n1] : (1.f - p[n1]);
    m *= ((L >> 1) & 1) ? p[n2] : (1.f - p[n2]);
    m *= (L & 1) ? p[n3] : (1.f - p[n3]);
    mixv[L] = m;
  }
  bf16* arow = Aact + (size_t)row * KEXT + NTOT;
  if (lane == 0) {
#pragma unroll
    for (int L = 0; L < NLEAF; ++L) {
      mg[row * NLEAF + L] = mixv[L];
      arow[L] = (bf16)mixv[L];
    }
  }
  if (lane >= 16) arow[lane] = (bf16)0.f;  // cols 4112..4159
}

// ---------------------------------------------------------------------------
// Shared GEMM helpers
template <int N>
__device__ __forceinline__ void wait_vmcnt() {
  asm volatile("s_waitcnt vmcnt(%0)" ::"n"(N) : "memory");
}
__device__ __forceinline__ void barrier_fence() {
  asm volatile("" ::: "memory");
  __builtin_amdgcn_s_barrier();
  asm volatile("" ::: "memory");
}

// ---------------------------------------------------------------------------
// GEMM1: Aact[:, :4096] = relu(Xbf[8192,1024] @ W1T[4096,1024]^T + b1) * mix
// 256x256 tile, 8 waves (2M x 4N), 4 phases/K-tile, ONE barrier per phase.
// Fragments read ONCE per K-tile and held in registers across their two
// consuming phases: phase order q(0,0) q(0,1) q(1,1) q(1,0);
//   reads: P00: A0+B0 (12), P01: B1 (4), P11: A1 (8), P10: none.
// Staging 1 tile ahead into nxt buf: P00->A0', P01->B0', P11->B1', P10->A1'.
// Counted vmcnt (never 0): P00:4 P01:4 P11:6 P10:4 (2 loads per half).
__global__ __launch_bounds__(512, 2) void gemm1_kernel(
    const bf16* __restrict__ A, const bf16* __restrict__ BT,
    const float* __restrict__ bias, const float* __restrict__ mg,
    bf16* __restrict__ outB) {
  constexpr int NT  = INF / 64;      // 16 K-tiles
  constexpr int ASZ = 256 * 64;      // elems per buf
  constexpr int BSZ = 256 * 64;
  __shared__ __align__(16) bf16 As[2 * ASZ];  // 64 KiB
  __shared__ __align__(16) bf16 Bs[2 * BSZ];  // 64 KiB

  const int t = threadIdx.x, lane = t & 63, w = t >> 6;
  const int wm = w >> 2, wn = w & 3;
  // XCD-bijective swizzle (512 % 8 == 0)
  const int orig = blockIdx.x;
  const int swz  = (orig & 7) * 64 + (orig >> 3);
  const int bm = (swz >> 4) * 256, bn = (swz & 15) * 256;
  // staging: thread -> (row lr, chunk cs); XOR pre-swizzled global col so
  // linear LDS + XOR read is conflict-free (same involution both sides).
  const int lr = t >> 3, cs = t & 7;
  const int scol = ((cs ^ (lr & 7)) << 3);

  auto stageA = [&](int kt, int h, int buf) {
#pragma unroll
    for (int q = 0; q < 2; ++q) {
      const bf16* src =
          A + (size_t)(bm + h * 128 + q * 64 + lr) * INF + kt * 64 + scol;
      __builtin_amdgcn_global_load_lds(
          (const __attribute__((address_space(1))) void*)src,
          (__attribute__((address_space(3))) void*)((char*)As +
                                                    buf * (ASZ * 2) +
                                                    h * 16384 + q * 8192 +
                                                    t * 16),
          16, 0, 0);
    }
  };
  auto stageB = [&](int kt, int h, int buf) {
#pragma unroll
    for (int q = 0; q < 2; ++q) {
      const bf16* src =
          BT + (size_t)(bn + h * 128 + q * 64 + lr) * INF + kt * 64 + scol;
      __builtin_amdgcn_global_load_lds(
          (const __attribute__((address_space(1))) void*)src,
          (__attribute__((address_space(3))) void*)((char*)Bs +
                                                    buf * (BSZ * 2) +
                                                    h * 16384 + q * 8192 +
                                                    t * 16),
          16, 0, 0);
    }
  };
  auto rdA = [&](int buf, int i, int kk) -> bf16x8 {
    int r  = wm * 64 + (i & 3) * 16 + (lane & 15);
    int ch = ((kk << 2) + (lane >> 4)) ^ (lane & 7);
    return *reinterpret_cast<const bf16x8*>(
        &As[buf * ASZ + (i >> 2) * 8192 + r * 64 + ch * 8]);
  };
  auto rdB = [&](int buf, int j, int kk) -> bf16x8 {
    int r  = wn * 32 + (j & 1) * 16 + (lane & 15);
    int ch = ((kk << 2) + (lane >> 4)) ^ (lane & 7);
    return *reinterpret_cast<const bf16x8*>(
        &Bs[buf * BSZ + (j >> 1) * 8192 + r * 64 + ch * 8]);
  };

  f32x4 acc[8][4];
#pragma unroll
  for (int i = 0; i < 8; ++i)
#pragma unroll
    for (int j = 0; j < 4; ++j) acc[i][j] = (f32x4){0.f, 0.f, 0.f, 0.f};

  // Prologue: tile0 halves in order A0,B0,B1,A1; vmcnt(4) leaves {B1,A1}.
  stageA(0, 0, 0);
  stageB(0, 0, 0);
  stageB(0, 1, 0);
  stageA(0, 1, 0);
  wait_vmcnt<4>();
  barrier_fence();

  for (int kt = 0; kt < NT; ++kt) {
    const int cur = kt & 1, nxt = cur ^ 1;
    const int k1 = kt + 1 < NT ? kt + 1 : NT - 1;  // clamp keeps counts
    bf16x8 af0[4][2], af1[4][2], bq0[2][2], bq1[2][2];

    // ---- P00: read A0,B0; stage (t+1).A0; MFMA quad (0,0)
#pragma unroll
    for (int i = 0; i < 4; ++i)
#pragma unroll
      for (int kk = 0; kk < 2; ++kk) af0[i][kk] = rdA(cur, i, kk);
#pragma unroll
    for (int j = 0; j < 2; ++j)
#pragma unroll
      for (int kk = 0; kk < 2; ++kk) bq0[j][kk] = rdB(cur, j, kk);
    stageA(k1, 0, nxt);
    __builtin_amdgcn_s_setprio(1);
#pragma unroll
    for (int kk = 0; kk < 2; ++kk)
#pragma unroll
      for (int i = 0; i < 4; ++i)
#pragma unroll
        for (int j = 0; j < 2; ++j)
          acc[i][j] = __builtin_amdgcn_mfma_f32_16x16x32_bf16(
              af0[i][kk], bq0[j][kk], acc[i][j], 0, 0, 0);
    __builtin_amdgcn_s_setprio(0);
    wait_vmcnt<4>();
    barrier_fence();

    // ---- P01: read B1; stage (t+1).B0; MFMA quad (0,1)
#pragma unroll
    for (int j = 0; j < 2; ++j)
#pragma unroll
      for (int kk = 0; kk < 2; ++kk) bq1[j][kk] = rdB(cur, 2 + j, kk);
    stageB(k1, 0, nxt);
    __builtin_amdgcn_s_setprio(1);
#pragma unroll
    for (int kk = 0; kk < 2; ++kk)
#pragma unroll
      for (int i = 0; i < 4; ++i)
#pragma unroll
        for (int j = 0; j < 2; ++j)
          acc[i][2 + j] = __builtin_amdgcn_mfma_f32_16x16x32_bf16(
              af0[i][kk], bq1[j][kk], acc[i][2 + j], 0, 0, 0);
    __builtin_amdgcn_s_setprio(0);
    wait_vmcnt<4>();
    barrier_fence();

    // ---- P11: read A1; stage (t+1).B1; MFMA quad (1,1)
#pragma unroll
    for (int i = 0; i < 4; ++i)
#pragma unroll
      for (int kk = 0; kk < 2; ++kk) af1[i][kk] = rdA(cur, 4 + i, kk);
    stageB(k1, 1, nxt);
    __builtin_amdgcn_s_setprio(1);
#pragma unroll
    for (int kk = 0; kk < 2; ++kk)
#pragma unroll
      for (int i = 0; i < 4; ++i)
#pragma unroll
        for (int j = 0; j < 2; ++j)
          acc[4 + i][2 + j] = __builtin_amdgcn_mfma_f32_16x16x32_bf16(
              af1[i][kk], bq1[j][kk], acc[4 + i][2 + j], 0, 0, 0);
    __builtin_amdgcn_s_setprio(0);
    wait_vmcnt<6>();
    barrier_fence();

    // ---- P10: stage (t+1).A1; MFMA quad (1,0) (af1, bq0 from registers)
    stageA(k1, 1, nxt);
    __builtin_amdgcn_s_setprio(1);
#pragma unroll
    for (int kk = 0; kk < 2; ++kk)
#pragma unroll
      for (int i = 0; i < 4; ++i)
#pragma unroll
        for (int j = 0; j < 2; ++j)
          acc[4 + i][j] = __builtin_amdgcn_mfma_f32_16x16x32_bf16(
              af1[i][kk], bq0[j][kk], acc[4 + i][j], 0, 0, 0);
    __builtin_amdgcn_s_setprio(0);
    wait_vmcnt<4>();
    barrier_fence();
  }

  // Epilogue: relu(acc + bias) * mg. C/D: col = lane&15, row = (lane>>4)*4+reg
  const int leaf = bn >> 8;  // BN=256 spans exactly one leaf
#pragma unroll
  for (int i = 0; i < 8; ++i) {
    int rb = bm + (i >> 2) * 128 + wm * 64 + (i & 3) * 16 + ((lane >> 4) << 2);
#pragma unroll
    for (int rr = 0; rr < 4; ++rr) {
      const int grow = rb + rr;
      const float g  = mg[grow * NLEAF + leaf];
#pragma unroll
      for (int j = 0; j < 4; ++j) {
        const int gcol =
            bn + (j >> 1) * 128 + wn * 32 + (j & 1) * 16 + (lane & 15);
        float v = acc[i][j][rr] + bias[gcol];
        v = v > 0.f ? v : 0.f;
        outB[(size_t)grow * KEXT + gcol] = (bf16)(v * g);
      }
    }
  }
}

// ---------------------------------------------------------------------------
// GEMM2: out[8192,1024] = Aact[8192,4160] @ W2T[1024,4160]^T
// 128x256 tile, 8 waves (2M x 4N), 2 phases/K-tile x 16 MFMA each.
//   reads: P0: A(8)+B0(4), P1: B1(4). Stage: P0->{A',B0'}, P1->{B1'}.
//   vmcnt: P0-end 4 (leaves A'+B0'), P1-end 2 (leaves B1'). Never 0.
__global__ __launch_bounds__(512, 2) void gemm2_kernel(
    const bf16* __restrict__ A, const bf16* __restrict__ BT,
    float* __restrict__ outF) {
  constexpr int NT  = KEXT / 64;     // 65 K-tiles
  constexpr int ASZ = 128 * 64;      // elems per buf (16 KiB)
  constexpr int BSZ = 256 * 64;      // 32 KiB
  __shared__ __align__(16) bf16 As[2 * ASZ];
  __shared__ __align__(16) bf16 Bs[2 * BSZ];

  const int t = threadIdx.x, lane = t & 63, w = t >> 6;
  const int wm = w >> 2, wn = w & 3;
  const int orig = blockIdx.x;
  const int swz  = (orig & 7) * 32 + (orig >> 3);  // 256 blocks
  const int bm = (swz >> 2) * 128, bn = (swz & 3) * 256;
  const int lr = t >> 3, cs = t & 7;
  const int scol = ((cs ^ (lr & 7)) << 3);

  auto stageA = [&](int kt, int buf) {
#pragma unroll
    for (int q = 0; q < 2; ++q) {
      const bf16* src =
          A + (size_t)(bm + q * 64 + lr) * KEXT + kt * 64 + scol;
      __builtin_amdgcn_global_load_lds(
          (const __attribute__((address_space(1))) void*)src,
          (__attribute__((address_space(3))) void*)((char*)As +
                                                    buf * (ASZ * 2) +
                                                    q * 8192 + t * 16),
          16, 0, 0);
    }
  };
  auto stageB = [&](int kt, int h, int buf) {
#pragma unroll
    for (int q = 0; q < 2; ++q) {
      const bf16* src =
          BT + (size_t)(bn + h * 128 + q * 64 + lr) * KEXT + kt * 64 + scol;
      __builtin_amdgcn_global_load_lds(
          (const __attribute__((address_space(1))) void*)src,
          (__attribute__((address_space(3))) void*)((char*)Bs +
                                                    buf * (BSZ * 2) +
                                                    h * 16384 + q * 8192 +
                                                    t * 16),
          16, 0, 0);
    }
  };
  auto rdA = [&](int buf, int i, int kk) -> bf16x8 {
    int r  = (i >> 1) * 64 + wm * 32 + (i & 1) * 16 + (lane & 15);
    int ch = ((kk << 2) + (lane >> 4)) ^ (lane & 7);
    return *reinterpret_cast<const bf16x8*>(
        &As[buf * ASZ + r * 64 + ch * 8]);
  };
  auto rdB = [&](int buf, int j, int kk) -> bf16x8 {
    int r  = wn * 32 + (j & 1) * 16 + (lane & 15);
    int ch = ((kk << 2) + (lane >> 4)) ^ (lane & 7);
    return *reinterpret_cast<const bf16x8*>(
        &Bs[buf * BSZ + (j >> 1) * 8192 + r * 64 + ch * 8]);
  };

  f32x4 acc[4][4];
#pragma unroll
  for (int i = 0; i < 4; ++i)
#pragma unroll
    for (int j = 0; j < 4; ++j) acc[i][j] = (f32x4){0.f, 0.f, 0.f, 0.f};

  // Prologue: tile0 {A,B0,B1}; vmcnt(2) leaves B1.
  stageA(0, 0);
  stageB(0, 0, 0);
  stageB(0, 1, 0);
  wait_vmcnt<2>();
  barrier_fence();

  for (int kt = 0; kt < NT; ++kt) {
    const int cur = kt & 1, nxt = cur ^ 1;
    const int k1 = kt + 1 < NT ? kt + 1 : NT - 1;
    bf16x8 af[4][2], bq0[2][2], bq1[2][2];

    // ---- P0: read A,B0; stage (t+1).{A,B0}; MFMA N-half 0
#pragma unroll
    for (int i = 0; i < 4; ++i)
#pragma unroll
      for (int kk = 0; kk < 2; ++kk) af[i][kk] = rdA(cur, i, kk);
#pragma unroll
    for (int j = 0; j < 2; ++j)
#pragma unroll
      for (int kk = 0; kk < 2; ++kk) bq0[j][kk] = rdB(cur, j, kk);
    stageA(k1, nxt);
    stageB(k1, 0, nxt);
    __builtin_amdgcn_s_setprio(1);
#pragma unroll
    for (int kk = 0; kk < 2; ++kk)
#pragma unroll
      for (int i = 0; i < 4; ++i)
#pragma unroll
        for (int j = 0; j < 2; ++j)
          acc[i][j] = __builtin_amdgcn_mfma_f32_16x16x32_bf16(
              af[i][kk], bq0[j][kk], acc[i][j], 0, 0, 0);
    __builtin_amdgcn_s_setprio(0);
    wait_vmcnt<4>();
    barrier_fence();

    // ---- P1: read B1; stage (t+1).B1; MFMA N-half 1
#pragma unroll
    for (int j = 0; j < 2; ++j)
#pragma unroll
      for (int kk = 0; kk < 2; ++kk) bq1[j][kk] = rdB(cur, 2 + j, kk);
    stageB(k1, 1, nxt);
    __builtin_amdgcn_s_setprio(1);
#pragma unroll
    for (int kk = 0; kk < 2; ++kk)
#pragma unroll
      for (int i = 0; i < 4; ++i)
#pragma unroll
        for (int j = 0; j < 2; ++j)
          acc[i][2 + j] = __builtin_amdgcn_mfma_f32_16x16x32_bf16(
              af[i][kk], bq1[j][kk], acc[i][2 + j], 0, 0, 0);
    __builtin_amdgcn_s_setprio(0);
    wait_vmcnt<2>();
    barrier_fence();
  }

  // Epilogue: fp32 store
#pragma unroll
  for (int i = 0; i < 4; ++i) {
    int rb = bm + (i >> 1) * 64 + wm * 32 + (i & 1) * 16 + ((lane >> 4) << 2);
#pragma unroll
    for (int rr = 0; rr < 4; ++rr) {
      const int grow = rb + rr;
#pragma unroll
      for (int j = 0; j < 4; ++j) {
        const int gcol =
            bn + (j >> 1) * 128 + wn * 32 + (j & 1) * 16 + (lane & 15);
        outF[(size_t)grow * OUTF + gcol] = acc[i][j][rr];
      }
    }
  }
}

// ---------------------------------------------------------------------------
extern "C" void kernel_launch(void* const* d_in, const int* in_sizes, int n_in,
                              void* d_out, int out_size, void* d_ws,
                              size_t ws_size, hipStream_t stream) {
  const float* x   = (const float*)d_in[0];  // [8192][1024]
  const float* nw  = (const float*)d_in[1];  // [15][1024]
  const float* nb  = (const float*)d_in[2];  // [15]
  const float* w1s = (const float*)d_in[3];  // [16][1024][256]
  const float* b1s = (const float*)d_in[4];  // [16][256] -> flat [4096]
  const float* w2s = (const float*)d_in[5];  // [16][256][1024]
  const float* b2s = (const float*)d_in[6];  // [16][1024]
  float* out = (float*)d_out;                // [8192][1024]

  char* ws = (char*)d_ws;
  bf16*  Xbf  = (bf16*)(ws);                  // 16,777,216 B
  bf16*  W1T  = (bf16*)(ws + 16777216);       //  8,388,608 B  [4096][1024]
  bf16*  W2T  = (bf16*)(ws + 25165824);       //  8,519,680 B  [1024][4160]
  float* mg   = (float*)(ws + 33685504);      //    524,288 B  [8192][16]
  bf16*  Aact = (bf16*)(ws + 34209792);       // 68,157,440 B  [8192][4160]

  prep_weights_kernel<<<dim3(8448), 256, 0, stream>>>(w1s, w2s, b2s, W1T, W2T);
  gating_kernel<<<dim3(BATCH / 4), 256, 0, stream>>>(
      (const float4*)x, (const float4*)nw, nb, mg, Aact, (bf16x4*)Xbf);

  // GEMM1: 256x256 tile, grid 32*16 = 512 blocks
  gemm1_kernel<<<dim3(512), 512, 0, stream>>>(Xbf, W1T, b1s, mg, Aact);
  // GEMM2: 128x256 tile, grid 64*4 = 256 blocks = full machine
  gemm2_kernel<<<dim3(256), 512, 0, stream>>>(Aact, W2T, out);
}